// Round 12
// baseline (106.346 us; speedup 1.0000x reference)
//
#include <hip/hip_runtime.h>
#include <hip/hip_bf16.h>

#define B_ROWS 4096
#define D_DIM  512
#define N_ROWS 8192
#define INV_T  20.0f
#define L2E_T  28.853900817779268f             // 20 / ln(2): exp(20x) = exp2(x*L2E_T)
#define EPS_N  1e-8f
#define CSPLIT 8
#define BM 256                                  // rows per block (= one panel)
#define BN 128                                  // cols per strip
#define COLS_PER_CHUNK (N_ROWS / CSPLIT)        // 1024
#define STRIPS (COLS_PER_CHUNK / BN)            // 8
#define NIT (STRIPS * 4)                        // 32 iters (K=128 each)
#define BUF_BYTES 16384                         // B tile: [4 kg][2 half][128 row][16B]
#define PANEL_BYTES 131072                      // [16 kg][2 half][256 row][16B]

typedef __attribute__((ext_vector_type(16))) float floatx16;
typedef __attribute__((ext_vector_type(8)))  int   intx8;
typedef __attribute__((ext_vector_type(4)))  int   intx4;

#define AS1C(p) ((const __attribute__((address_space(1))) void*)(p))
#define AS3(p)  ((__attribute__((address_space(3))) void*)(p))
#define CAT8(a, b) __builtin_shufflevector((a), (b), 0, 1, 2, 3, 4, 5, 6, 7)

// MX scale 1.0 in E8M0 (bias 127); opsel=0 picks byte 0
#define SC1 0x7F7F7F7F
#define MXMFMA(A, B, C) \
  __builtin_amdgcn_mfma_scale_f32_32x32x64_f8f6f4((A), (B), (C), 0, 0, 0, SC1, 0, SC1)

// sorted-insert via med3: new_t[i] = median(v, t[i], t[i-1]); all-ILP
__device__ __forceinline__ void insert5(float (&t)[5], float v) {
  float n0 = fmaxf(t[0], v);
  float n1 = __builtin_amdgcn_fmed3f(v, t[1], t[0]);
  float n2 = __builtin_amdgcn_fmed3f(v, t[2], t[1]);
  float n3 = __builtin_amdgcn_fmed3f(v, t[3], t[2]);
  float n4 = __builtin_amdgcn_fmed3f(v, t[4], t[3]);
  t[0] = n0; t[1] = n1; t[2] = n2; t[3] = n3; t[4] = n4;
}

// scan one strip: exp-sum + top-5 (diag already poisoned to -inf)
__device__ __forceinline__ void scan_acc(floatx16 (&acc)[2], float (&sum)[2],
                                         float (&top)[2][5]) {
  #pragma unroll
  for (int rb = 0; rb < 2; ++rb)
    #pragma unroll
    for (int r = 0; r < 16; ++r) {
      float ev = exp2f(acc[rb][r] * L2E_T);
      sum[rb] += ev;
      insert5(top[rb], ev);
    }
}

// ---- kernel 1: normalize -> fp8 e4m3 in panel/kg/half16 layout, dot(f1,f2) ----
__global__ __launch_bounds__(256) void prep_kernel(
    const float* __restrict__ f1, const float* __restrict__ f2,
    unsigned char* __restrict__ fnb8, float* __restrict__ dots)
{
  int row = blockIdx.x;          // 0..4095
  int t = threadIdx.x;
  const float* r1 = f1 + (size_t)row * D_DIM;
  const float* r2 = f2 + (size_t)row * D_DIM;
  float2 a = *(const float2*)(r1 + 2 * t);
  float2 b = *(const float2*)(r2 + 2 * t);
  float s1 = a.x * a.x + a.y * a.y;
  float s2 = b.x * b.x + b.y * b.y;
  float d  = a.x * b.x + a.y * b.y;
  #pragma unroll
  for (int off = 32; off >= 1; off >>= 1) {
    s1 += __shfl_down(s1, off);
    s2 += __shfl_down(s2, off);
    d  += __shfl_down(d, off);
  }
  __shared__ float red[4][3];
  __shared__ float bc[2];
  int wave = t >> 6, lane = t & 63;
  if (lane == 0) { red[wave][0] = s1; red[wave][1] = s2; red[wave][2] = d; }
  __syncthreads();
  if (t == 0) {
    float S1 = red[0][0] + red[1][0] + red[2][0] + red[3][0];
    float S2 = red[0][1] + red[1][1] + red[2][1] + red[3][1];
    float Dd = red[0][2] + red[1][2] + red[2][2] + red[3][2];
    bc[0] = 1.0f / fmaxf(sqrtf(S1), EPS_N);
    bc[1] = 1.0f / fmaxf(sqrtf(S2), EPS_N);
    dots[row] = Dd;
  }
  __syncthreads();
  // phase 2: threads 0-63 pack f1, 64-127 pack f2; thread handles 8 fp8 bytes
  if (t < 128) {
    int q = t & 63;                        // 8-byte group within the row's K
    int is2 = t >> 6;
    const float* src = (is2 ? f2 : f1) + (size_t)row * D_DIM + q * 8;
    float sc = bc[is2];
    float4 v0 = *(const float4*)(src);
    float4 v1 = *(const float4*)(src + 4);
    int lo = __builtin_amdgcn_cvt_pk_fp8_f32(v0.x * sc, v0.y * sc, 0, false);
    lo     = __builtin_amdgcn_cvt_pk_fp8_f32(v0.z * sc, v0.w * sc, lo, true);
    int hi = __builtin_amdgcn_cvt_pk_fp8_f32(v1.x * sc, v1.y * sc, 0, false);
    hi     = __builtin_amdgcn_cvt_pk_fp8_f32(v1.z * sc, v1.w * sc, hi, true);
    int grow = row + is2 * B_ROWS;
    int panel = grow >> 8, rin = grow & 255;
    int kg = q >> 2;                       // 32B k-group 0..15
    int rem = q & 3;                       // 8B slot within 32B
    int half = rem >> 1, inner = (rem & 1) * 8;
    int2 pack; pack.x = lo; pack.y = hi;
    *(int2*)(fnb8 + (size_t)panel * PANEL_BYTES + kg * 8192 + half * 4096
             + rin * 16 + inner) = pack;
  }
}

// ---- kernel 2: MX fp8 32x32x64 swapped-operand MFMA; A direct global->reg,
// B staged in LDS (plane-split, conflict-free); in-register exp-sum/top-5 ----
// 1024 thr, 4x4 wave grid, wave tile 64 rows x 32 cols, acc[2] (32 AGPR)
__global__ __launch_bounds__(1024, 4) void sim_kernel(
    const unsigned char* __restrict__ fnb8,
    float* __restrict__ partials)      // [N_ROWS][CSPLIT][6] = sum, top5 (desc)
{
  __shared__ int4 lds4[2048];          // 32 KiB = 2 B-tile buffers
  char* lds = (char*)lds4;

  // XCD-bijective mapping: XCD (bx&7) owns rowtiles 4x..4x+3 across all chunks
  int bx = blockIdx.x;                 // 0..255
  int xcd = bx & 7, kk = bx >> 3;      // kk: 0..31
  int rt = xcd * 4 + (kk & 3);         // 0..31  (= A panel index)
  int chunk = kk >> 2;                 // 0..7
  int rowbase = rt * BM;
  int chunkbase = chunk * COLS_PER_CHUNK;

  int t = threadIdx.x;
  int wave = t >> 6, lane = t & 63;
  int wr = wave >> 2, wc = wave & 3;   // 4x4 wave grid; wave tile 64 x 32
  int l31 = lane & 31, lh = lane >> 5;

  int r0 = wr * 64 + l31;              // A rows per lane
  int r1 = r0 + 32;
  int bcol16 = (wc * 32 + l31) * 16;   // B col byte offset within a plane

  // staging decomposition: wave stages 1 KB: kg = w>>2, half = (w>>1)&1, sub = w&1
  int skg = wave >> 2, shalf = (wave >> 1) & 1, ssub = wave & 1;
  int soff = skg * 4096 + shalf * 2048 + ssub * 1024 + lane * 16;   // LDS dst
  int sgsub = shalf * 4096 + ssub * 1024 + lane * 16;               // src sub-offset

  float sum[2];
  float top[2][5];
  floatx16 acc[2];
  #pragma unroll
  for (int rb = 0; rb < 2; ++rb) {
    sum[rb] = 0.f;
    #pragma unroll
    for (int k = 0; k < 5; ++k) top[rb][k] = 0.f;
    #pragma unroll
    for (int e = 0; e < 16; ++e) acc[rb][e] = 0.0f;
  }

  const char* gA  = (const char*)fnb8 + (size_t)rt * PANEL_BYTES;
  const char* gB0 = (const char*)fnb8 + (size_t)(chunk * 4) * PANEL_BYTES;

  // prologue: stage B tile for it=0 (strip 0, kiter 0)
  __builtin_amdgcn_global_load_lds(AS1C(gB0 + skg * 8192 + sgsub),
                                   AS3(lds + soff), 16, 0, 0);
  __syncthreads();                     // drains vmcnt -> tile 0 resident

  for (int it = 0; it < NIT; ++it) {
    int strip = it >> 2, kiter = it & 3, cur = it & 1;

    if (it + 1 < NIT) {
      int ns = (it + 1) >> 2, nk = (it + 1) & 3;
      const char* bp = gB0 + (size_t)(ns >> 1) * PANEL_BYTES + ((ns & 1) * 128) * 16;
      __builtin_amdgcn_global_load_lds(AS1C(bp + (nk * 4 + skg) * 8192 + sgsub),
                                       AS3(lds + (cur ^ 1) * BUF_BYTES + soff), 16, 0, 0);
    }

    const char* Bs = lds + cur * BUF_BYTES;
    __builtin_amdgcn_s_setprio(1);
    #pragma unroll
    for (int m = 0; m < 2; ++m) {
      int kg = m * 2 + lh;             // local k-group 0..3
      const char* abase = gA + (kiter * 4 + kg) * 8192;
      intx4 a00 = *(const intx4*)(abase + r0 * 16);          // row0 half0
      intx4 a01 = *(const intx4*)(abase + 4096 + r0 * 16);   // row0 half1
      intx4 a10 = *(const intx4*)(abase + r1 * 16);
      intx4 a11 = *(const intx4*)(abase + 4096 + r1 * 16);
      const char* bbase = Bs + kg * 4096 + bcol16;
      intx4 b0 = *(const intx4*)(bbase);
      intx4 b1 = *(const intx4*)(bbase + 2048);
      intx8 cf = CAT8(b0, b1);
      acc[0] = MXMFMA(cf, CAT8(a00, a01), acc[0]);
      acc[1] = MXMFMA(cf, CAT8(a10, a11), acc[1]);
    }
    __builtin_amdgcn_s_setprio(0);

    if (kiter == 3) {                  // strip complete: poison diag, scan, reset
      int d = (chunkbase + strip * BN + wc * 32) - (rowbase + wr * 64);
      if ((d == 0 || d == 32) && lh == ((l31 >> 2) & 1)) {
        int rd = (l31 & 3) | (((l31 >> 3) & 3) << 2);
        acc[d >> 5][rd] = -1e30f;      // exp2 -> 0 (exact diag exclusion)
      }
      scan_acc(acc, sum, top);
      #pragma unroll
      for (int rb = 0; rb < 2; ++rb)
        #pragma unroll
        for (int e = 0; e < 16; ++e) acc[rb][e] = 0.0f;
    }

    __syncthreads();                   // reads of cur done + next tile resident
  }

  // merge lane l <-> l+32 (same sim-rows, disjoint col subsets)
  #pragma unroll
  for (int rb = 0; rb < 2; ++rb) {
    sum[rb] += __shfl_xor(sum[rb], 32);
    float pt[5];
    #pragma unroll
    for (int k = 0; k < 5; ++k) pt[k] = __shfl_xor(top[rb][k], 32);
    #pragma unroll
    for (int k = 0; k < 5; ++k) insert5(top[rb], pt[k]);
  }

  // cross-wave merge: 4 wc-waves hold disjoint col ranges of the same rows
  float* mbuf = (float*)lds;           // [16 waves][2 rb][32 lanes][6] = 24 KiB
  __syncthreads();                     // tiles dead; safe to reuse LDS
  if (lane < 32) {
    #pragma unroll
    for (int rb = 0; rb < 2; ++rb) {
      float* dst = mbuf + (size_t)(((wave * 2 + rb) * 32) + lane) * 6;
      dst[0] = sum[rb];
      #pragma unroll
      for (int k = 0; k < 5; ++k) dst[1 + k] = top[rb][k];
    }
  }
  __syncthreads();
  if (t < 256) {                       // thread t owns block-row t
    int wr2 = t >> 6, rb2 = (t >> 5) & 1, r31 = t & 31;
    float s = 0.0f;
    float a5[5] = {0.f, 0.f, 0.f, 0.f, 0.f};
    #pragma unroll
    for (int wc2 = 0; wc2 < 4; ++wc2) {
      int w = wr2 * 4 + wc2;
      const float* src = mbuf + (size_t)(((w * 2 + rb2) * 32) + r31) * 6;
      s += src[0];
      #pragma unroll
      for (int k = 0; k < 5; ++k) insert5(a5, src[1 + k]);
    }
    int grow = rowbase + t;
    float* dst = partials + ((size_t)grow * CSPLIT + chunk) * 6;
    dst[0] = s;
    #pragma unroll
    for (int k = 0; k < 5; ++k) dst[1 + k] = a5[k];
  }
}

// -------------------- kernel 3a: per-row loss, 32-block partial sums ----------
__global__ __launch_bounds__(256) void finalize1_kernel(
    const float* __restrict__ partials, const float* __restrict__ dots,
    float* __restrict__ bpart)
{
  int row = blockIdx.x * 256 + threadIdx.x;    // 32*256 = 8192
  const float* p = partials + (size_t)row * (CSPLIT * 6);
  float s = 0.0f;
  float a5[5] = {0.f, 0.f, 0.f, 0.f, 0.f};
  #pragma unroll
  for (int c = 0; c < CSPLIT; ++c) {
    s += p[c * 6];
    #pragma unroll
    for (int k = 0; k < 5; ++k) insert5(a5, p[c * 6 + 1 + k]);
  }
  float ng = s - (a5[0] + a5[1] + a5[2] + a5[3] + a5[4]);
  float dv = dots[row & (B_ROWS - 1)];
  float acc = __logf(ng + __expf(dv * INV_T)) - dv * INV_T;

  #pragma unroll
  for (int off = 32; off >= 1; off >>= 1) acc += __shfl_down(acc, off);
  __shared__ float red[4];
  int wave = threadIdx.x >> 6, lane = threadIdx.x & 63;
  if (lane == 0) red[wave] = acc;
  __syncthreads();
  if (threadIdx.x == 0)
    bpart[blockIdx.x] = red[0] + red[1] + red[2] + red[3];
}

// -------------------- kernel 3b: final reduce --------------------
__global__ __launch_bounds__(64) void finalize2_kernel(
    const float* __restrict__ bpart, float* __restrict__ out)
{
  int t = threadIdx.x;
  float v = (t < 32) ? bpart[t] : 0.0f;
  #pragma unroll
  for (int off = 32; off >= 1; off >>= 1) v += __shfl_down(v, off);
  if (t == 0) out[0] = v / (float)N_ROWS;
}

extern "C" void kernel_launch(void* const* d_in, const int* in_sizes, int n_in,
                              void* d_out, int out_size, void* d_ws, size_t ws_size,
                              hipStream_t stream) {
  const float* f1 = (const float*)d_in[0];
  const float* f2 = (const float*)d_in[1];
  float* out = (float*)d_out;
  char* ws = (char*)d_ws;

  unsigned char* fnb8 = (unsigned char*)ws;                           // 4 MiB
  float* dots = (float*)(ws + (size_t)4 * 1024 * 1024);               // 16 KiB
  float* partials = (float*)(ws + (size_t)4 * 1024 * 1024 + 65536);   // 1.5 MiB
  float* bpart = (float*)(ws + (size_t)8 * 1024 * 1024);              // 128 B

  prep_kernel<<<B_ROWS, 256, 0, stream>>>(f1, f2, fnb8, dots);
  sim_kernel<<<(N_ROWS / BM) * CSPLIT, 1024, 0, stream>>>(fnb8, partials);
  finalize1_kernel<<<32, 256, 0, stream>>>(partials, dots, bpart);
  finalize2_kernel<<<1, 64, 0, stream>>>(bpart, out);
}

// Round 13
// 59.801 us; speedup vs baseline: 1.7783x; 1.7783x over previous
//
#include <hip/hip_runtime.h>
#include <hip/hip_bf16.h>

#define B_ROWS 4096
#define D_DIM  512
#define N_ROWS 8192
#define EPS_N  1e-8f
#define INV_T  20.0f
// exp(20*sim) = exp2(acc * FACT); acc = 1024*sim (global fp4 scale 2^-5 on both operands)
#define FACT   0.0281778328298626f             // 20 / ln(2) / 1024
#define CSPLIT 8
#define BM 256                                  // rows per block (= one panel)
#define BN 256                                  // cols per strip (= one panel)
#define COLS_PER_CHUNK (N_ROWS / CSPLIT)        // 1024
#define STRIPS (COLS_PER_CHUNK / BN)            // 4
#define NIT (STRIPS * 4)                        // 16 iters (K=128 each)
#define TILE_BYTES 16384                        // [4 kg][256 row][16B] fp4
#define BUF_BYTES  32768                        // A + B per buffer
#define PANEL_BYTES 65536                       // [16 kg][256 row][16B] per 256-row panel
#define KITER_BYTES 16384                       // K=128 = 4 kg x 4KB

typedef __attribute__((ext_vector_type(16))) float floatx16;
typedef __attribute__((ext_vector_type(8)))  int   intx8;
typedef __attribute__((ext_vector_type(4)))  int   intx4;

#define AS1C(p) ((const __attribute__((address_space(1))) void*)(p))
#define AS3(p)  ((__attribute__((address_space(3))) void*)(p))

// MX scale 1.0 in E8M0 (bias 127); opsel=0 picks byte 0. cbsz=blgp=4 -> fp4 e2m1
#define SC1 0x7F7F7F7F
#define MXMFMA4(A, B, C) \
  __builtin_amdgcn_mfma_scale_f32_32x32x64_f8f6f4((A), (B), (C), 4, 4, 0, SC1, 0, SC1)

// fp4 LDS tile: [4 kg][256 row][16B]; 32 lanes read 512B contiguous -> conflict-free
__device__ __forceinline__ intx4 ldsFrag16(const char* base, int row, int kg) {
  return *(const intx4*)(base + kg * 4096 + row * 16);
}

// sorted-insert via med3: new_t[i] = median(v, t[i], t[i-1]); all-ILP
__device__ __forceinline__ void insert5(float (&t)[5], float v) {
  float n0 = fmaxf(t[0], v);
  float n1 = __builtin_amdgcn_fmed3f(v, t[1], t[0]);
  float n2 = __builtin_amdgcn_fmed3f(v, t[2], t[1]);
  float n3 = __builtin_amdgcn_fmed3f(v, t[3], t[2]);
  float n4 = __builtin_amdgcn_fmed3f(v, t[4], t[3]);
  t[0] = n0; t[1] = n1; t[2] = n2; t[3] = n3; t[4] = n4;
}

// scan one strip: exp-sum + top-5 (diag already poisoned to -inf)
__device__ __forceinline__ void scan_acc(floatx16 (&acc)[2][2], float (&sum)[2],
                                         float (&top)[2][5]) {
  #pragma unroll
  for (int rb = 0; rb < 2; ++rb)
    #pragma unroll
    for (int cb = 0; cb < 2; ++cb)
      #pragma unroll
      for (int r = 0; r < 16; ++r) {
        float ev = exp2f(acc[rb][cb][r] * FACT);
        sum[rb] += ev;
        insert5(top[rb], ev);
      }
}

// e2m1 encode (RNE): values {0,.5,1,1.5,2,3,4,6}, sign in bit 3
__device__ __forceinline__ unsigned enc_fp4(float y) {
  float f = fminf(fabsf(y), 6.0f);
  float c1 = rintf(f + f);                       // f < 2  -> codes 0..4
  float c2 = rintf(f - 2.0f) + 4.0f;             // 2<=f<4 -> codes 4..6
  float c3 = rintf((f - 4.0f) * 0.5f) + 6.0f;    // f>=4   -> codes 6..7
  float c = (f < 2.0f) ? c1 : ((f < 4.0f) ? c2 : c3);
  return (unsigned)c | ((__float_as_uint(y) >> 31) << 3);
}

// stage one K=128 step: A tile (16KB) + B tile (16KB), contiguous identity copies.
// 16 waves x 2KB each (2 x 16B-wide global_load_lds).
__device__ __forceinline__ void stage_tile(const char* gA_t, const char* gB_t,
                                           char* buf, int wave, int lane) {
  const char* src = ((wave < 8) ? gA_t : gB_t) + (wave & 7) * 2048 + lane * 16;
  char* dst = buf + ((wave < 8) ? 0 : TILE_BYTES) + (wave & 7) * 2048;
  #pragma unroll
  for (int q = 0; q < 2; ++q)
    __builtin_amdgcn_global_load_lds(AS1C(src + q * 1024), AS3(dst + q * 1024), 16, 0, 0);
}

// ---- kernel 1: normalize -> fp4 e2m1 (scale 2^-5) in panel/kg layout, dot(f1,f2) ----
__global__ __launch_bounds__(256) void prep_kernel(
    const float* __restrict__ f1, const float* __restrict__ f2,
    unsigned char* __restrict__ fnb4, float* __restrict__ dots)
{
  int row = blockIdx.x;          // 0..4095
  int t = threadIdx.x;
  const float* r1 = f1 + (size_t)row * D_DIM;
  const float* r2 = f2 + (size_t)row * D_DIM;
  float2 a = *(const float2*)(r1 + 2 * t);
  float2 b = *(const float2*)(r2 + 2 * t);
  float s1 = a.x * a.x + a.y * a.y;
  float s2 = b.x * b.x + b.y * b.y;
  float d  = a.x * b.x + a.y * b.y;
  #pragma unroll
  for (int off = 32; off >= 1; off >>= 1) {
    s1 += __shfl_down(s1, off);
    s2 += __shfl_down(s2, off);
    d  += __shfl_down(d, off);
  }
  __shared__ float red[4][3];
  __shared__ float bc[2];
  int wave = t >> 6, lane = t & 63;
  if (lane == 0) { red[wave][0] = s1; red[wave][1] = s2; red[wave][2] = d; }
  __syncthreads();
  if (t == 0) {
    float S1 = red[0][0] + red[1][0] + red[2][0] + red[3][0];
    float S2 = red[0][1] + red[1][1] + red[2][1] + red[3][1];
    float Dd = red[0][2] + red[1][2] + red[2][2] + red[3][2];
    bc[0] = 1.0f / fmaxf(sqrtf(S1), EPS_N);
    bc[1] = 1.0f / fmaxf(sqrtf(S2), EPS_N);
    dots[row] = Dd;
  }
  __syncthreads();
  // phase 2: threads 0-63 pack f1, 64-127 pack f2; thread handles 8 elems -> one u32
  if (t < 128) {
    int q = t & 63;                        // 8-elem group within the row's K
    int is2 = t >> 6;
    const float* src = (is2 ? f2 : f1) + (size_t)row * D_DIM + q * 8;
    float sc = bc[is2] * 32.0f;            // normalize then / 2^-5
    float4 v0 = *(const float4*)(src);
    float4 v1 = *(const float4*)(src + 4);
    unsigned p = enc_fp4(v0.x * sc);
    p |= enc_fp4(v0.y * sc) << 4;
    p |= enc_fp4(v0.z * sc) << 8;
    p |= enc_fp4(v0.w * sc) << 12;
    p |= enc_fp4(v1.x * sc) << 16;
    p |= enc_fp4(v1.y * sc) << 20;
    p |= enc_fp4(v1.z * sc) << 24;
    p |= enc_fp4(v1.w * sc) << 28;
    int grow = row + is2 * B_ROWS;
    int panel = grow >> 8, rin = grow & 255;
    int kg = q >> 2;                       // 32-elem k-group 0..15
    *(unsigned*)(fnb4 + (size_t)panel * PANEL_BYTES + kg * 4096 + rin * 16
                 + (q & 3) * 4) = p;
  }
}

// ---- kernel 2: MX fp4 32x32x64 swapped-operand MFMA + in-register exp-sum/top-5 ----
// 1024 thr, 4x4 wave grid, wave tile 64x64; K=128 per buffer, 16 barriers
__global__ __launch_bounds__(1024, 4) void sim_kernel(
    const unsigned char* __restrict__ fnb4,
    float* __restrict__ partials)      // [N_ROWS][CSPLIT][6] = sum, top5 (desc)
{
  __shared__ int4 lds4[4096];          // 64 KiB = 2 buffers of (A 16KB + B 16KB)
  char* lds = (char*)lds4;

  // XCD-bijective mapping: XCD (bx&7) owns rowtiles 4x..4x+3 across all chunks
  int bx = blockIdx.x;                 // 0..255
  int xcd = bx & 7, kk = bx >> 3;      // kk: 0..31
  int rt = xcd * 4 + (kk & 3);         // 0..31  (= A panel index)
  int chunk = kk >> 2;                 // 0..7
  int rowbase = rt * BM;
  int chunkbase = chunk * COLS_PER_CHUNK;

  int t = threadIdx.x;
  int wave = t >> 6, lane = t & 63;
  int wr = wave >> 2, wc = wave & 3;   // 4x4 wave grid; wave tile 64x64
  int l31 = lane & 31, lh = lane >> 5;

  float sum[2];
  float top[2][5];
  floatx16 acc[2][2];
  #pragma unroll
  for (int rb = 0; rb < 2; ++rb) {
    sum[rb] = 0.f;
    #pragma unroll
    for (int k = 0; k < 5; ++k) top[rb][k] = 0.f;
    #pragma unroll
    for (int cb = 0; cb < 2; ++cb)
      #pragma unroll
      for (int e = 0; e < 16; ++e) acc[rb][cb][e] = 0.0f;
  }

  const char* gA  = (const char*)fnb4 + (size_t)rt * PANEL_BYTES;
  const char* gB0 = (const char*)fnb4 + (size_t)(chunk * 4) * PANEL_BYTES;

  stage_tile(gA, gB0, lds, wave, lane);
  __syncthreads();                     // drains vmcnt -> tile 0 resident

  intx4 z4 = {0, 0, 0, 0};
  for (int it = 0; it < NIT; ++it) {
    int strip = it >> 2, kstep = it & 3, cur = it & 1;

    if (it + 1 < NIT) {
      int ns = (it + 1) >> 2, nk = (it + 1) & 3;
      stage_tile(gA + nk * KITER_BYTES,
                 gB0 + (size_t)ns * PANEL_BYTES + nk * KITER_BYTES,
                 lds + (cur ^ 1) * BUF_BYTES, wave, lane);
    }

    const char* As = lds + cur * BUF_BYTES;
    const char* Bs = As + TILE_BYTES;
    __builtin_amdgcn_s_setprio(1);
    #pragma unroll
    for (int m = 0; m < 2; ++m) {
      int kg = m * 2 + lh;             // kgroup 0..3 within buffer
      intx4 rf0 = ldsFrag16(As, wr * 64 + l31,      kg);
      intx4 rf1 = ldsFrag16(As, wr * 64 + 32 + l31, kg);
      intx4 cf0 = ldsFrag16(Bs, wc * 64 + l31,      kg);
      intx4 cf1 = ldsFrag16(Bs, wc * 64 + 32 + l31, kg);
      intx8 R0 = __builtin_shufflevector(rf0, z4, 0, 1, 2, 3, 4, 5, 6, 7);
      intx8 R1 = __builtin_shufflevector(rf1, z4, 0, 1, 2, 3, 4, 5, 6, 7);
      intx8 C0 = __builtin_shufflevector(cf0, z4, 0, 1, 2, 3, 4, 5, 6, 7);
      intx8 C1 = __builtin_shufflevector(cf1, z4, 0, 1, 2, 3, 4, 5, 6, 7);
      acc[0][0] = MXMFMA4(C0, R0, acc[0][0]);
      acc[0][1] = MXMFMA4(C1, R0, acc[0][1]);
      acc[1][0] = MXMFMA4(C0, R1, acc[1][0]);
      acc[1][1] = MXMFMA4(C1, R1, acc[1][1]);
    }
    __builtin_amdgcn_s_setprio(0);

    if (kstep == 3) {                  // strip complete: poison diag, scan, reset
      // diagonal sub-block: this wave's rows == this strip's cols (wave-uniform)
      bool dwave = (rowbase + wr * 64) == (chunkbase + strip * BN + wc * 64);
      if (dwave && (((l31 >> 2) & 1) == lh)) {
        int rd = (l31 & 3) | (((l31 >> 3) & 3) << 2);
        acc[0][0][rd] = -1e30f;        // exp2 -> 0 (exact diag exclusion)
        acc[1][1][rd] = -1e30f;
      }
      scan_acc(acc, sum, top);
      #pragma unroll
      for (int rb = 0; rb < 2; ++rb)
        #pragma unroll
        for (int cb = 0; cb < 2; ++cb)
          #pragma unroll
          for (int e = 0; e < 16; ++e) acc[rb][cb][e] = 0.0f;
    }

    __syncthreads();                   // reads of cur done + next tile resident
  }

  // merge lane l <-> l+32 (same sim-rows, disjoint col subsets)
  #pragma unroll
  for (int rb = 0; rb < 2; ++rb) {
    sum[rb] += __shfl_xor(sum[rb], 32);
    float pt[5];
    #pragma unroll
    for (int k = 0; k < 5; ++k) pt[k] = __shfl_xor(top[rb][k], 32);
    #pragma unroll
    for (int k = 0; k < 5; ++k) insert5(top[rb], pt[k]);
  }

  // cross-wave merge: 4 wc-waves hold disjoint col ranges of the same rows
  float* mbuf = (float*)lds;           // [16 waves][2 rb][32 lanes][6] = 24 KiB
  if (lane < 32) {
    #pragma unroll
    for (int rb = 0; rb < 2; ++rb) {
      float* dst = mbuf + (size_t)(((wave * 2 + rb) * 32) + lane) * 6;
      dst[0] = sum[rb];
      #pragma unroll
      for (int k = 0; k < 5; ++k) dst[1 + k] = top[rb][k];
    }
  }
  __syncthreads();
  if (t < 256) {                       // thread t owns block-row t
    int wr2 = t >> 6, rb2 = (t >> 5) & 1, r31 = t & 31;
    float s = 0.0f;
    float a5[5] = {0.f, 0.f, 0.f, 0.f, 0.f};
    #pragma unroll
    for (int wc2 = 0; wc2 < 4; ++wc2) {
      int w = wr2 * 4 + wc2;
      const float* src = mbuf + (size_t)(((w * 2 + rb2) * 32) + r31) * 6;
      s += src[0];
      #pragma unroll
      for (int k = 0; k < 5; ++k) insert5(a5, src[1 + k]);
    }
    int grow = rowbase + t;
    float* dst = partials + ((size_t)grow * CSPLIT + chunk) * 6;
    dst[0] = s;
    #pragma unroll
    for (int k = 0; k < 5; ++k) dst[1 + k] = a5[k];
  }
}

// -------------------- kernel 3a: per-row loss, 32-block partial sums ----------
__global__ __launch_bounds__(256) void finalize1_kernel(
    const float* __restrict__ partials, const float* __restrict__ dots,
    float* __restrict__ bpart)
{
  int row = blockIdx.x * 256 + threadIdx.x;    // 32*256 = 8192
  const float* p = partials + (size_t)row * (CSPLIT * 6);
  float s = 0.0f;
  float a5[5] = {0.f, 0.f, 0.f, 0.f, 0.f};
  #pragma unroll
  for (int c = 0; c < CSPLIT; ++c) {
    s += p[c * 6];
    #pragma unroll
    for (int k = 0; k < 5; ++k) insert5(a5, p[c * 6 + 1 + k]);
  }
  float ng = s - (a5[0] + a5[1] + a5[2] + a5[3] + a5[4]);
  float dv = dots[row & (B_ROWS - 1)];
  float acc = __logf(ng + __expf(dv * INV_T)) - dv * INV_T;

  #pragma unroll
  for (int off = 32; off >= 1; off >>= 1) acc += __shfl_down(acc, off);
  __shared__ float red[4];
  int wave = threadIdx.x >> 6, lane = threadIdx.x & 63;
  if (lane == 0) red[wave] = acc;
  __syncthreads();
  if (threadIdx.x == 0)
    bpart[blockIdx.x] = red[0] + red[1] + red[2] + red[3];
}

// -------------------- kernel 3b: final reduce --------------------
__global__ __launch_bounds__(64) void finalize2_kernel(
    const float* __restrict__ bpart, float* __restrict__ out)
{
  int t = threadIdx.x;
  float v = (t < 32) ? bpart[t] : 0.0f;
  #pragma unroll
  for (int off = 32; off >= 1; off >>= 1) v += __shfl_down(v, off);
  if (t == 0) out[0] = v / (float)N_ROWS;
}

extern "C" void kernel_launch(void* const* d_in, const int* in_sizes, int n_in,
                              void* d_out, int out_size, void* d_ws, size_t ws_size,
                              hipStream_t stream) {
  const float* f1 = (const float*)d_in[0];
  const float* f2 = (const float*)d_in[1];
  float* out = (float*)d_out;
  char* ws = (char*)d_ws;

  unsigned char* fnb4 = (unsigned char*)ws;                           // 2 MiB
  float* dots = (float*)(ws + (size_t)4 * 1024 * 1024);               // 16 KiB
  float* partials = (float*)(ws + (size_t)4 * 1024 * 1024 + 65536);   // 1.5 MiB
  float* bpart = (float*)(ws + (size_t)8 * 1024 * 1024);              // 128 B

  prep_kernel<<<B_ROWS, 256, 0, stream>>>(f1, f2, fnb4, dots);
  sim_kernel<<<(N_ROWS / BM) * CSPLIT, 1024, 0, stream>>>(fnb4, partials);
  finalize1_kernel<<<32, 256, 0, stream>>>(partials, dots, bpart);
  finalize2_kernel<<<1, 64, 0, stream>>>(bpart, out);
}